// Round 10
// baseline (504.650 us; speedup 1.0000x reference)
//
#include <hip/hip_runtime.h>
#include <hip/hip_bf16.h>

#define BATCH 8192
#define DIM   2048

typedef __attribute__((ext_vector_type(8))) short  bf16x8;
typedef __attribute__((ext_vector_type(4))) float  f32x4;

__device__ __forceinline__ unsigned short f2bf(float f) {
    __hip_bfloat16 h = __float2bfloat16(f);
    return *reinterpret_cast<unsigned short*>(&h);
}

// jax.nn.gelu approximate=True: 0.5x(1+tanh(y)) == x*sigmoid(2y), y=c0(x+0.044715x^3)
__device__ __forceinline__ float gelu_f(float x) {
    float z = -1.5957691216057308f * (x + 0.044715f * x * x * x);  // -2*c0*(...)
    return x / (1.0f + __expf(z));
}

__device__ __forceinline__ void gload_lds16(const void* g, void* lds) {
    __builtin_amdgcn_global_load_lds(
        (const __attribute__((address_space(1))) unsigned int*)g,
        (__attribute__((address_space(3))) unsigned int*)lds,
        16, 0, 0);
}

// ---------------- routing ----------------
__global__ void minmax_k(const float* __restrict__ u, float* __restrict__ mm,
                         int* __restrict__ flags, int n) {
    __shared__ float smn[1024], smx[1024];
    int t = threadIdx.x;
    if (t < 2) flags[t] = 0;
    const float4* p = reinterpret_cast<const float4*>(u);
    float4 a = p[2 * t], b = p[2 * t + 1];
    float mn = fminf(fminf(fminf(a.x, a.y), fminf(a.z, a.w)),
                     fminf(fminf(b.x, b.y), fminf(b.z, b.w)));
    float mx = fmaxf(fmaxf(fmaxf(a.x, a.y), fmaxf(a.z, a.w)),
                     fmaxf(fmaxf(b.x, b.y), fmaxf(b.z, b.w)));
    smn[t] = mn; smx[t] = mx;
    __syncthreads();
    for (int s = 512; s > 0; s >>= 1) {
        if (t < s) {
            smn[t] = fminf(smn[t], smn[t + s]);
            smx[t] = fmaxf(smx[t], smx[t + s]);
        }
        __syncthreads();
    }
    if (t == 0) { mm[0] = smn[0]; mm[1] = smx[0]; }
}

// Router weights staged in LDS (fixes the 165us serial-s_load pathology, r2).
__global__ void route_k(const float* __restrict__ unc, const float* __restrict__ mm,
                        const float* __restrict__ rw1, const float* __restrict__ rb1,
                        const float* __restrict__ rw2, const float* __restrict__ rb2,
                        const float* __restrict__ rw3, const float* __restrict__ rb3,
                        int* __restrict__ routing, float* __restrict__ mask_out,
                        int* __restrict__ flags, int n) {
    __shared__ float s_w1[32], s_b1[32], s_w2[512], s_b2[16], s_w3[48], s_b3[3];
    const int t = threadIdx.x;
    if (t < 32) { s_w1[t] = rw1[t]; s_b1[t] = rb1[t]; }
#pragma unroll
    for (int i2 = 0; i2 < 2; ++i2) s_w2[i2 * 256 + t] = rw2[i2 * 256 + t];
    if (t < 16) s_b2[t] = rb2[t];
    if (t < 48) s_w3[t] = rw3[t];
    if (t < 3)  s_b3[t] = rb3[t];
    __syncthreads();

    int i = blockIdx.x * 256 + t;
    float u = (unc[i] - mm[0]) / (mm[1] - mm[0] + 1e-8f);
    float h1[32];
#pragma unroll
    for (int j = 0; j < 32; ++j) h1[j] = fmaxf(u * s_w1[j] + s_b1[j], 0.0f);
    float h2[16];
#pragma unroll
    for (int j = 0; j < 16; ++j) {
        float s = s_b2[j];
#pragma unroll
        for (int k = 0; k < 32; ++k) s += h1[k] * s_w2[k * 16 + j];
        h2[j] = fmaxf(s, 0.0f);
    }
    float lg[3];
#pragma unroll
    for (int j = 0; j < 3; ++j) {
        float s = s_b3[j];
#pragma unroll
        for (int k = 0; k < 16; ++k) s += h2[k] * s_w3[k * 3 + j];
        lg[j] = s;
    }
    // argmax(softmax) == argmax(logits); strict '>' = first-index ties (jnp.argmax)
    int idx = 0; float best = lg[0];
    if (lg[1] > best) { best = lg[1]; idx = 1; }
    if (lg[2] > best) { best = lg[2]; idx = 2; }
    routing[i] = idx;
    mask_out[i] = (float)idx;

    unsigned long long b1 = __ballot(idx >= 1);
    unsigned long long b2 = __ballot(idx >= 2);
    if ((t & 63) == 0) {
        if (b1) atomicOr(&flags[0], 1);
        if (b2) atomicOr(&flags[1], 1);
    }
}

// ---------------- conversions ----------------
__global__ void convx_k(const float* __restrict__ in, unsigned short* __restrict__ out, int n8) {
    int i = blockIdx.x * 256 + threadIdx.x;
    if (i >= n8) return;
    const float4* p = reinterpret_cast<const float4*>(in) + (size_t)2 * i;
    float4 a = p[0], b = p[1];
    bf16x8 o;
    o[0] = (short)f2bf(a.x); o[1] = (short)f2bf(a.y);
    o[2] = (short)f2bf(a.z); o[3] = (short)f2bf(a.w);
    o[4] = (short)f2bf(b.x); o[5] = (short)f2bf(b.y);
    o[6] = (short)f2bf(b.z); o[7] = (short)f2bf(b.w);
    *(reinterpret_cast<bf16x8*>(out) + i) = o;
}

// W [K][N] f32 -> Wt [N][K] bf16, 64x64 tile, full-line coalesced IO (r9).
__global__ void convw_k(const float* __restrict__ W, unsigned short* __restrict__ Wt,
                        const int* __restrict__ flags, int need_lvl) {
    if (need_lvl > 0 && flags[need_lvl - 1] == 0) return;
    __shared__ float lds[64 * 65];
    const int t  = threadIdx.x;          // 256
    const int n0 = blockIdx.x * 64, k0 = blockIdx.y * 64;
    const int c4 = t & 15;               // float4 col
#pragma unroll
    for (int i = 0; i < 4; ++i) {
        int r = (t >> 4) + 16 * i;       // k row 0..63
        float4 v = *(const float4*)(W + (size_t)(k0 + r) * DIM + n0 + c4 * 4);
        lds[r * 65 + c4 * 4 + 0] = v.x;
        lds[r * 65 + c4 * 4 + 1] = v.y;
        lds[r * 65 + c4 * 4 + 2] = v.z;
        lds[r * 65 + c4 * 4 + 3] = v.w;
    }
    __syncthreads();
#pragma unroll
    for (int i = 0; i < 2; ++i) {
        int c2 = t + 256 * i;            // 0..511
        int n  = c2 >> 3;                // out row 0..63
        int kc = c2 & 7;                 // 8-elem k chunk
        bf16x8 o;
#pragma unroll
        for (int j = 0; j < 8; ++j) o[j] = (short)f2bf(lds[(kc * 8 + j) * 65 + n]);
        *(bf16x8*)(Wt + (size_t)(n0 + n) * DIM + k0 + kc * 8) = o;
    }
}

// ---------------- 256x256 GEMM, 1-barrier-per-K-tile (AITER-shape) ----------------
// C[m][n] = gelu(sum_k A[m][k] * Bt[n][k] + bias[n])
// BM=BN=256, BK=64, 512 thr = 8 waves (2M x 4N). LDS 128KiB = 2 dbuf x (A32K|B32K).
// Within a tile there is NO LDS hazard (reads hit buf, stage writes hit nb), so the
// only sync is one vmcnt(0)+s_barrier at tile entry (stage(t) was issued a full
// tile earlier -> wait is cheap). Interior (24 ds_read_b128 + 64 MFMA per wave)
// is compiler-scheduled with fine-grained lgkmcnt; ~64 MFMA per barrier.
// 16B-chunk XOR swizzle (chunk ^= row&7) on BOTH sides (0 conflicts, r6-r9).
__launch_bounds__(512, 2)
__global__ void gemm_k(const unsigned short* __restrict__ A,
                       const unsigned short* __restrict__ Bt,
                       unsigned short* __restrict__ Ob,   // [M][N] bf16 scratch out
                       const float* __restrict__ bias,    // [N]
                       const int* __restrict__ routing,
                       float* __restrict__ Of,            // [M][N] f32 final out
                       int match, int store_ob, int need_lvl) {
    constexpr int N = DIM, K = DIM;
    constexpr int NT = K / 64;            // 32 K-tiles
    __shared__ char smem[131072];
    __shared__ int s_need;

    const int tid = threadIdx.x;
    // XCD-contiguous remap: 256 wgs, 8 XCDs -> XCD x owns wg [x*32, x*32+32)
    const int wg  = (blockIdx.x & 7) * 32 + (blockIdx.x >> 3);
    const int bm  = wg >> 3;              // 32 M-tiles
    const int bn  = wg & 7;               // 8 N-tiles
    const int m0  = bm * 256, n0 = bn * 256;

    if (need_lvl > 0) {
        if (tid == 0) s_need = 0;
        __syncthreads();
        if (tid < 256 && routing[m0 + tid] >= need_lvl) atomicOr(&s_need, 1);
        __syncthreads();
        if (s_need == 0) return;
    }

    const int wave = tid >> 6, lane = tid & 63;
    const int wm = wave >> 2, wn = wave & 3;      // 2M x 4N wave grid

    // ---- staging (linear LDS dest, inverse-swizzled global src) ----
    const int srow = tid >> 3;                              // 0..63
    const int sw8  = ((tid & 7) ^ (srow & 7)) << 3;         // inv-swizzled elem col
    const unsigned short* gA0 = A  + (size_t)(m0 + srow) * K + sw8;
    const unsigned short* gB0 = Bt + (size_t)(n0 + srow) * K + sw8;
    const int ldsw = wave * 1024;
    auto STAGE = [&](const unsigned short* gb, int koff, int lo) {
        gload_lds16(gb + koff,                  smem + lo + ldsw);
        gload_lds16(gb + (size_t)64 * K + koff, smem + lo + 8192 + ldsw);
    };
    const unsigned short* gA1 = gA0 + (size_t)128 * K;
    const unsigned short* gB1 = gB0 + (size_t)128 * K;

    f32x4 acc[8][4];
#pragma unroll
    for (int i = 0; i < 8; ++i)
#pragma unroll
        for (int j = 0; j < 4; ++j)
            acc[i][j] = (f32x4){0.f, 0.f, 0.f, 0.f};

    const int lrow = lane & 15;
    const int ck0 = (((lane >> 4)    ) ^ (lane & 7)) << 4;   // swizzled 16B chunk, ks=0
    const int ck1 = (((lane >> 4) + 4) ^ (lane & 7)) << 4;   // ks=1

    // prologue: stage tile 0
    STAGE(gA0, 0, 0);
    STAGE(gA1, 0, 16384);
    STAGE(gB0, 0, 32768);
    STAGE(gB1, 0, 49152);

    for (int t = 0; t < NT; ++t) {
        const int bsel = (t & 1) << 16;
        const char* buf = smem + bsel;
        const int nb   = bsel ^ 65536;
        const int ko   = (t + 1) << 6;
        const bool pre = (t + 1 < NT);

        // tile entry: stage(t) complete (issued one full tile ago -> cheap wait);
        // barrier also proves all waves consumed nb as tile t-1 -> safe to overwrite.
        asm volatile("s_waitcnt vmcnt(0)" ::: "memory");
        asm volatile("s_barrier" ::: "memory");

        // issue next tile's stage immediately; lands under this tile's compute
        if (pre) {
            STAGE(gA0, ko, nb);
            STAGE(gA1, ko, nb + 16384);
            STAGE(gB0, ko, nb + 32768);
            STAGE(gB1, ko, nb + 49152);
        }

        bf16x8 aF[4][2], bL[2][2], bH[2][2];
        // Q00: A-low x B-low
#pragma unroll
        for (int f = 0; f < 4; ++f) {
            int ro = (f * 32 + wm * 16 + lrow) * 128;
            aF[f][0] = *(const bf16x8*)(buf + ro + ck0);
            aF[f][1] = *(const bf16x8*)(buf + ro + ck1);
        }
#pragma unroll
        for (int g = 0; g < 2; ++g) {
            int ro = 32768 + (g * 64 + wn * 16 + lrow) * 128;
            bL[g][0] = *(const bf16x8*)(buf + ro + ck0);
            bL[g][1] = *(const bf16x8*)(buf + ro + ck1);
        }
        __builtin_amdgcn_s_setprio(1);
#pragma unroll
        for (int ks = 0; ks < 2; ++ks)
#pragma unroll
            for (int f = 0; f < 4; ++f)
#pragma unroll
                for (int g = 0; g < 2; ++g)
                    acc[f][g] = __builtin_amdgcn_mfma_f32_16x16x32_bf16(
                        aF[f][ks], bL[g][ks], acc[f][g], 0, 0, 0);
        __builtin_amdgcn_s_setprio(0);

        // Q01: A-low x B-high
#pragma unroll
        for (int g = 0; g < 2; ++g) {
            int ro = 32768 + (128 + g * 64 + wn * 16 + lrow) * 128;
            bH[g][0] = *(const bf16x8*)(buf + ro + ck0);
            bH[g][1] = *(const bf16x8*)(buf + ro + ck1);
        }
        __builtin_amdgcn_s_setprio(1);
#pragma unroll
        for (int ks = 0; ks < 2; ++ks)
#pragma unroll
            for (int f = 0; f < 4; ++f)
#pragma unroll
                for (int g = 0; g < 2; ++g)
                    acc[f][2 + g] = __builtin_amdgcn_mfma_f32_16x16x32_bf16(
                        aF[f][ks], bH[g][ks], acc[f][2 + g], 0, 0, 0);
        __builtin_amdgcn_s_setprio(0);

        // Q11: A-high x B-high
#pragma unroll
        for (int f = 0; f < 4; ++f) {
            int ro = (128 + f * 32 + wm * 16 + lrow) * 128;
            aF[f][0] = *(const bf16x8*)(buf + ro + ck0);
            aF[f][1] = *(const bf16x8*)(buf + ro + ck1);
        }
        __builtin_amdgcn_s_setprio(1);
#pragma unroll
        for (int ks = 0; ks < 2; ++ks)
#pragma unroll
            for (int f = 0; f < 4; ++f)
#pragma unroll
                for (int g = 0; g < 2; ++g)
                    acc[4 + f][2 + g] = __builtin_amdgcn_mfma_f32_16x16x32_bf16(
                        aF[f][ks], bH[g][ks], acc[4 + f][2 + g], 0, 0, 0);
        __builtin_amdgcn_s_setprio(0);

        // Q10: A-high x B-low
        __builtin_amdgcn_s_setprio(1);
#pragma unroll
        for (int ks = 0; ks < 2; ++ks)
#pragma unroll
            for (int f = 0; f < 4; ++f)
#pragma unroll
                for (int g = 0; g < 2; ++g)
                    acc[4 + f][g] = __builtin_amdgcn_mfma_f32_16x16x32_bf16(
                        aF[f][ks], bL[g][ks], acc[4 + f][g], 0, 0, 0);
        __builtin_amdgcn_s_setprio(0);
    }

    // ---- epilogue: C col = lane&15, row = (lane>>4)*4 + rr; direct stores ----
    // frag->coord: row = m0 + (mf&3)*32 + (mf>>2)*128 + wm*16 + rsub + rr
    //              col = n0 + nf*64 + wn*16 + lrow
    const int c0 = n0 + wn * 16;
    float bcol[4];
#pragma unroll
    for (int nf = 0; nf < 4; ++nf) bcol[nf] = bias[c0 + nf * 64 + lrow];
    const int rsub = (lane >> 4) * 4;

#pragma unroll
    for (int mf = 0; mf < 8; ++mf) {
        const int rbase = m0 + (mf & 3) * 32 + (mf >> 2) * 128 + wm * 16 + rsub;
#pragma unroll
        for (int rr = 0; rr < 4; ++rr) {
            int row = rbase + rr;
            int rt  = routing[row];
            size_t base = (size_t)row * N + c0 + lrow;
#pragma unroll
            for (int nf = 0; nf < 4; ++nf) {
                float v = gelu_f(acc[mf][nf][rr] + bcol[nf]);
                if (store_ob)    Ob[base + nf * 64] = f2bf(v);
                if (rt == match) Of[base + nf * 64] = v;
            }
        }
    }
}

extern "C" void kernel_launch(void* const* d_in, const int* in_sizes, int n_in,
                              void* d_out, int out_size, void* d_ws, size_t ws_size,
                              hipStream_t stream) {
    const float* x   = (const float*)d_in[0];
    const float* unc = (const float*)d_in[1];
    const float* Ws  = (const float*)d_in[2];
    const float* bs  = (const float*)d_in[3];
    const float* rw1 = (const float*)d_in[4];
    const float* rb1 = (const float*)d_in[5];
    const float* rw2 = (const float*)d_in[6];
    const float* rb2 = (const float*)d_in[7];
    const float* rw3 = (const float*)d_in[8];
    const float* rb3 = (const float*)d_in[9];
    float* out  = (float*)d_out;
    float* mask = out + (size_t)BATCH * DIM;

    // ws layout: Wb (8MB) | hb0 (32MB) | hb1 (32MB) | routing (32KB) | mm | flags
    char* ws = (char*)d_ws;
    unsigned short* Wb  = (unsigned short*)ws;
    unsigned short* hb0 = (unsigned short*)(ws + (size_t)8  * 1024 * 1024);
    unsigned short* hb1 = (unsigned short*)(ws + (size_t)40 * 1024 * 1024);
    int*   routing = (int*)  (ws + (size_t)72 * 1024 * 1024);
    float* mm      = (float*)(ws + (size_t)72 * 1024 * 1024 + 64 * 1024);
    int*   flags   = (int*)  (ws + (size_t)72 * 1024 * 1024 + 64 * 1024 + 16);

    minmax_k<<<1, 1024, 0, stream>>>(unc, mm, flags, BATCH);
    route_k<<<BATCH / 256, 256, 0, stream>>>(unc, mm, rw1, rb1, rw2, rb2, rw3, rb3,
                                             routing, mask, flags, BATCH);
    convx_k<<<(BATCH * DIM / 8 + 255) / 256, 256, 0, stream>>>(x, hb0, BATCH * DIM / 8);

    // chain: hb0(x) -W0-> hb1(lvl0) -W1-> hb0(lvl1) -W2-> hb1 -W3-> (lvl2, no Ob)
    const unsigned short* ins[4]  = {hb0, hb1, hb0, hb1};
    unsigned short*       outs[4] = {hb1, hb0, hb1, hb0};
    const int matches[4]   = {0, 1, -1, 2};
    const int store_ob[4]  = {1, 1, 1, 0};
    const int need_lvl[4]  = {0, 1, 2, 2};
    for (int l = 0; l < 4; ++l) {
        convw_k<<<dim3(32, 32), 256, 0, stream>>>(Ws + (size_t)l * DIM * DIM, Wb,
                                                  flags, need_lvl[l]);
        gemm_k<<<256, 512, 0, stream>>>(ins[l], Wb, outs[l], bs + (size_t)l * DIM,
                                        routing, out, matches[l], store_ob[l], need_lvl[l]);
    }
}

// Round 11
// 464.257 us; speedup vs baseline: 1.0870x; 1.0870x over previous
//
#include <hip/hip_runtime.h>
#include <hip/hip_bf16.h>

#define BATCH 8192
#define DIM   2048

typedef __attribute__((ext_vector_type(8))) short  bf16x8;
typedef __attribute__((ext_vector_type(4))) float  f32x4;

__device__ __forceinline__ unsigned short f2bf(float f) {
    __hip_bfloat16 h = __float2bfloat16(f);
    return *reinterpret_cast<unsigned short*>(&h);
}

// jax.nn.gelu approximate=True: 0.5x(1+tanh(y)) == x*sigmoid(2y), y=c0(x+0.044715x^3)
__device__ __forceinline__ float gelu_f(float x) {
    float z = -1.5957691216057308f * (x + 0.044715f * x * x * x);  // -2*c0*(...)
    return x / (1.0f + __expf(z));
}

__device__ __forceinline__ void gload_lds16(const void* g, void* lds) {
    __builtin_amdgcn_global_load_lds(
        (const __attribute__((address_space(1))) unsigned int*)g,
        (__attribute__((address_space(3))) unsigned int*)lds,
        16, 0, 0);
}

// ---------------- routing ----------------
__global__ void minmax_k(const float* __restrict__ u, float* __restrict__ mm,
                         int* __restrict__ flags, int n) {
    __shared__ float smn[1024], smx[1024];
    int t = threadIdx.x;
    if (t < 2) flags[t] = 0;
    const float4* p = reinterpret_cast<const float4*>(u);
    float4 a = p[2 * t], b = p[2 * t + 1];
    float mn = fminf(fminf(fminf(a.x, a.y), fminf(a.z, a.w)),
                     fminf(fminf(b.x, b.y), fminf(b.z, b.w)));
    float mx = fmaxf(fmaxf(fmaxf(a.x, a.y), fmaxf(a.z, a.w)),
                     fmaxf(fmaxf(b.x, b.y), fmaxf(b.z, b.w)));
    smn[t] = mn; smx[t] = mx;
    __syncthreads();
    for (int s = 512; s > 0; s >>= 1) {
        if (t < s) {
            smn[t] = fminf(smn[t], smn[t + s]);
            smx[t] = fmaxf(smx[t], smx[t + s]);
        }
        __syncthreads();
    }
    if (t == 0) { mm[0] = smn[0]; mm[1] = smx[0]; }
}

// Router weights staged in LDS (fixes the 165us serial-s_load pathology, r2).
__global__ void route_k(const float* __restrict__ unc, const float* __restrict__ mm,
                        const float* __restrict__ rw1, const float* __restrict__ rb1,
                        const float* __restrict__ rw2, const float* __restrict__ rb2,
                        const float* __restrict__ rw3, const float* __restrict__ rb3,
                        int* __restrict__ routing, float* __restrict__ mask_out,
                        int* __restrict__ flags, int n) {
    __shared__ float s_w1[32], s_b1[32], s_w2[512], s_b2[16], s_w3[48], s_b3[3];
    const int t = threadIdx.x;
    if (t < 32) { s_w1[t] = rw1[t]; s_b1[t] = rb1[t]; }
#pragma unroll
    for (int i2 = 0; i2 < 2; ++i2) s_w2[i2 * 256 + t] = rw2[i2 * 256 + t];
    if (t < 16) s_b2[t] = rb2[t];
    if (t < 48) s_w3[t] = rw3[t];
    if (t < 3)  s_b3[t] = rb3[t];
    __syncthreads();

    int i = blockIdx.x * 256 + t;
    float u = (unc[i] - mm[0]) / (mm[1] - mm[0] + 1e-8f);
    float h1[32];
#pragma unroll
    for (int j = 0; j < 32; ++j) h1[j] = fmaxf(u * s_w1[j] + s_b1[j], 0.0f);
    float h2[16];
#pragma unroll
    for (int j = 0; j < 16; ++j) {
        float s = s_b2[j];
#pragma unroll
        for (int k = 0; k < 32; ++k) s += h1[k] * s_w2[k * 16 + j];
        h2[j] = fmaxf(s, 0.0f);
    }
    float lg[3];
#pragma unroll
    for (int j = 0; j < 3; ++j) {
        float s = s_b3[j];
#pragma unroll
        for (int k = 0; k < 16; ++k) s += h2[k] * s_w3[k * 3 + j];
        lg[j] = s;
    }
    // argmax(softmax) == argmax(logits); strict '>' = first-index ties (jnp.argmax)
    int idx = 0; float best = lg[0];
    if (lg[1] > best) { best = lg[1]; idx = 1; }
    if (lg[2] > best) { best = lg[2]; idx = 2; }
    routing[i] = idx;
    mask_out[i] = (float)idx;

    unsigned long long b1 = __ballot(idx >= 1);
    unsigned long long b2 = __ballot(idx >= 2);
    if ((t & 63) == 0) {
        if (b1) atomicOr(&flags[0], 1);
        if (b2) atomicOr(&flags[1], 1);
    }
}

// ---------------- conversions ----------------
__global__ void convx_k(const float* __restrict__ in, unsigned short* __restrict__ out, int n8) {
    int i = blockIdx.x * 256 + threadIdx.x;
    if (i >= n8) return;
    const float4* p = reinterpret_cast<const float4*>(in) + (size_t)2 * i;
    float4 a = p[0], b = p[1];
    bf16x8 o;
    o[0] = (short)f2bf(a.x); o[1] = (short)f2bf(a.y);
    o[2] = (short)f2bf(a.z); o[3] = (short)f2bf(a.w);
    o[4] = (short)f2bf(b.x); o[5] = (short)f2bf(b.y);
    o[6] = (short)f2bf(b.z); o[7] = (short)f2bf(b.w);
    *(reinterpret_cast<bf16x8*>(out) + i) = o;
}

// W [K][N] f32 -> Wt [N][K] bf16, 64x64 tile, full-line coalesced IO (r9).
__global__ void convw_k(const float* __restrict__ W, unsigned short* __restrict__ Wt,
                        const int* __restrict__ flags, int need_lvl) {
    if (need_lvl > 0 && flags[need_lvl - 1] == 0) return;
    __shared__ float lds[64 * 65];
    const int t  = threadIdx.x;          // 256
    const int n0 = blockIdx.x * 64, k0 = blockIdx.y * 64;
    const int c4 = t & 15;               // float4 col
#pragma unroll
    for (int i = 0; i < 4; ++i) {
        int r = (t >> 4) + 16 * i;       // k row 0..63
        float4 v = *(const float4*)(W + (size_t)(k0 + r) * DIM + n0 + c4 * 4);
        lds[r * 65 + c4 * 4 + 0] = v.x;
        lds[r * 65 + c4 * 4 + 1] = v.y;
        lds[r * 65 + c4 * 4 + 2] = v.z;
        lds[r * 65 + c4 * 4 + 3] = v.w;
    }
    __syncthreads();
#pragma unroll
    for (int i = 0; i < 2; ++i) {
        int c2 = t + 256 * i;            // 0..511
        int n  = c2 >> 3;                // out row 0..63
        int kc = c2 & 7;                 // 8-elem k chunk
        bf16x8 o;
#pragma unroll
        for (int j = 0; j < 8; ++j) o[j] = (short)f2bf(lds[(kc * 8 + j) * 65 + n]);
        *(bf16x8*)(Wt + (size_t)(n0 + n) * DIM + k0 + kc * 8) = o;
    }
}

// ---------------- 256x256 8-phase GEMM, counted-vmcnt, 3-barrier/tile ----------------
// C[m][n] = gelu(sum_k A[m][k] * Bt[n][k] + bias[n])
// r9 structure (83us) minus the non-load-bearing barriers. Only barriers that
// publish a vmcnt wait remain: B0 (P0, after vmcnt(6): B1(t) visible),
// B1 (P1, after vmcnt(6): A1(t) visible), B3 (P3, after vmcnt(4): A0B0(t+1)
// visible). Hazard proof: every phase's buf-reads are lgkm-drained before its
// MFMAs, hence complete before that wave reaches B3; stage writes always target
// nb; forward-running waves are gated by B3 before touching the swapped buffer.
// Removed barriers convert wave skew into cross-wave LDS-read/MFMA overlap.
__launch_bounds__(512, 2)
__global__ void gemm_k(const unsigned short* __restrict__ A,
                       const unsigned short* __restrict__ Bt,
                       unsigned short* __restrict__ Ob,   // [M][N] bf16 scratch out
                       const float* __restrict__ bias,    // [N]
                       const int* __restrict__ routing,
                       float* __restrict__ Of,            // [M][N] f32 final out
                       int match, int store_ob, int need_lvl) {
    constexpr int N = DIM, K = DIM;
    constexpr int NT = K / 64;            // 32 K-tiles
    __shared__ char smem[131072];
    __shared__ int s_need;

    const int tid = threadIdx.x;
    // XCD-contiguous remap: 256 wgs, 8 XCDs -> XCD x owns wg [x*32, x*32+32)
    const int wg  = (blockIdx.x & 7) * 32 + (blockIdx.x >> 3);
    const int bm  = wg >> 3;              // 32 M-tiles
    const int bn  = wg & 7;               // 8 N-tiles
    const int m0  = bm * 256, n0 = bn * 256;

    if (need_lvl > 0) {
        if (tid == 0) s_need = 0;
        __syncthreads();
        if (tid < 256 && routing[m0 + tid] >= need_lvl) atomicOr(&s_need, 1);
        __syncthreads();
        if (s_need == 0) return;
    }

    const int wave = tid >> 6, lane = tid & 63;
    const int wm = wave >> 2, wn = wave & 3;      // 2M x 4N wave grid

    // ---- staging (linear LDS dest, inverse-swizzled global src) ----
    const int srow = tid >> 3;                              // 0..63
    const int sw8  = ((tid & 7) ^ (srow & 7)) << 3;         // inv-swizzled elem col
    const unsigned short* gA0 = A  + (size_t)(m0 + srow) * K + sw8;
    const unsigned short* gB0 = Bt + (size_t)(n0 + srow) * K + sw8;
    const int ldsw = wave * 1024;
    auto STAGE = [&](const unsigned short* gb, int koff, int lo) {
        gload_lds16(gb + koff,                  smem + lo + ldsw);
        gload_lds16(gb + (size_t)64 * K + koff, smem + lo + 8192 + ldsw);
    };
    const unsigned short* gA1 = gA0 + (size_t)128 * K;
    const unsigned short* gB1 = gB0 + (size_t)128 * K;

    f32x4 acc[8][4];
#pragma unroll
    for (int i = 0; i < 8; ++i)
#pragma unroll
        for (int j = 0; j < 4; ++j)
            acc[i][j] = (f32x4){0.f, 0.f, 0.f, 0.f};

    const int lrow = lane & 15;
    const int ck0 = (((lane >> 4)    ) ^ (lane & 7)) << 4;   // swizzled 16B chunk, ks=0
    const int ck1 = (((lane >> 4) + 4) ^ (lane & 7)) << 4;   // ks=1
    // per-lane LDS base offsets (constant across tiles); reads use imm offsets
    const int bA0 = (wm * 16 + lrow) * 128 + ck0;
    const int bA1 = (wm * 16 + lrow) * 128 + ck1;
    const int bB0 = 32768 + (wn * 16 + lrow) * 128 + ck0;
    const int bB1 = 32768 + (wn * 16 + lrow) * 128 + ck1;

    // prologue: stage tile 0 (order A0,B0,B1,A1), wait A0+B0, barrier
    STAGE(gA0, 0, 0);
    STAGE(gB0, 0, 32768);
    STAGE(gB1, 0, 49152);
    STAGE(gA1, 0, 16384);
    asm volatile("s_waitcnt vmcnt(4)" ::: "memory");
    __builtin_amdgcn_s_barrier();

    for (int t = 0; t < NT; ++t) {
        const char* buf = smem + ((t & 1) << 16);
        const int nb   = ((t & 1) << 16) ^ 65536;
        const int ko   = (t + 1) << 6;    // next tile's k elem offset
        const bool pre = (t + 1 < NT);
        const char* pA0 = buf + bA0;
        const char* pA1 = buf + bA1;
        const char* pB0 = buf + bB0;
        const char* pB1 = buf + bB1;
        bf16x8 aF[4][2], bL[2][2], bH[2][2];

        // ---- P0: read A-low + B-low; stage A0,B0(t+1); vmcnt(6); BARRIER
#pragma unroll
        for (int f = 0; f < 4; ++f) {
            aF[f][0] = *(const bf16x8*)(pA0 + f * 4096);
            aF[f][1] = *(const bf16x8*)(pA1 + f * 4096);
        }
#pragma unroll
        for (int g = 0; g < 2; ++g) {
            bL[g][0] = *(const bf16x8*)(pB0 + g * 8192);
            bL[g][1] = *(const bf16x8*)(pB1 + g * 8192);
        }
        if (pre) {
            STAGE(gA0, ko, nb);
            STAGE(gB0, ko, nb + 32768);
            asm volatile("s_waitcnt vmcnt(6)" ::: "memory");
        } else {
            asm volatile("s_waitcnt vmcnt(2)" ::: "memory");
        }
        __builtin_amdgcn_s_barrier();
        asm volatile("s_waitcnt lgkmcnt(0)" ::: "memory");
        __builtin_amdgcn_sched_barrier(0);
        __builtin_amdgcn_s_setprio(1);
#pragma unroll
        for (int ks = 0; ks < 2; ++ks)
#pragma unroll
            for (int f = 0; f < 4; ++f)
#pragma unroll
                for (int g = 0; g < 2; ++g)
                    acc[f][g] = __builtin_amdgcn_mfma_f32_16x16x32_bf16(
                        aF[f][ks], bL[g][ks], acc[f][g], 0, 0, 0);
        __builtin_amdgcn_s_setprio(0);
        // (no post-MFMA barrier)

        // ---- P1: read B-high; stage B1(t+1); vmcnt(6); BARRIER
#pragma unroll
        for (int g = 0; g < 2; ++g) {
            bH[g][0] = *(const bf16x8*)(pB0 + 16384 + g * 8192);
            bH[g][1] = *(const bf16x8*)(pB1 + 16384 + g * 8192);
        }
        if (pre) {
            STAGE(gB1, ko, nb + 49152);
            asm volatile("s_waitcnt vmcnt(6)" ::: "memory");
        } else {
            asm volatile("s_waitcnt vmcnt(0)" ::: "memory");
        }
        __builtin_amdgcn_s_barrier();
        asm volatile("s_waitcnt lgkmcnt(0)" ::: "memory");
        __builtin_amdgcn_sched_barrier(0);
        __builtin_amdgcn_s_setprio(1);
#pragma unroll
        for (int ks = 0; ks < 2; ++ks)
#pragma unroll
            for (int f = 0; f < 4; ++f)
#pragma unroll
                for (int g = 0; g < 2; ++g)
                    acc[f][2 + g] = __builtin_amdgcn_mfma_f32_16x16x32_bf16(
                        aF[f][ks], bH[g][ks], acc[f][2 + g], 0, 0, 0);
        __builtin_amdgcn_s_setprio(0);
        // (no post-MFMA barrier)

        // ---- P2: read A-high; stage A1(t+1); no barrier (A1(t) visible since B1)
#pragma unroll
        for (int f = 0; f < 4; ++f) {
            aF[f][0] = *(const bf16x8*)(pA0 + 16384 + f * 4096);
            aF[f][1] = *(const bf16x8*)(pA1 + 16384 + f * 4096);
        }
        if (pre) STAGE(gA1, ko, nb + 16384);
        asm volatile("s_waitcnt lgkmcnt(0)" ::: "memory");
        __builtin_amdgcn_sched_barrier(0);
        __builtin_amdgcn_s_setprio(1);
#pragma unroll
        for (int ks = 0; ks < 2; ++ks)
#pragma unroll
            for (int f = 0; f < 4; ++f)
#pragma unroll
                for (int g = 0; g < 2; ++g)
                    acc[4 + f][2 + g] = __builtin_amdgcn_mfma_f32_16x16x32_bf16(
                        aF[f][ks], bH[g][ks], acc[4 + f][2 + g], 0, 0, 0);
        __builtin_amdgcn_s_setprio(0);

        // ---- P3: pure MFMA; tile-boundary counted wait vmcnt(4); BARRIER
        if (pre) asm volatile("s_waitcnt vmcnt(4)" ::: "memory");
        __builtin_amdgcn_s_barrier();
        __builtin_amdgcn_s_setprio(1);
#pragma unroll
        for (int ks = 0; ks < 2; ++ks)
#pragma unroll
            for (int f = 0; f < 4; ++f)
#pragma unroll
                for (int g = 0; g < 2; ++g)
                    acc[4 + f][g] = __builtin_amdgcn_mfma_f32_16x16x32_bf16(
                        aF[f][ks], bL[g][ks], acc[4 + f][g], 0, 0, 0);
        __builtin_amdgcn_s_setprio(0);
        // (no post-MFMA barrier: next P0's reads are gated by this tile's B3)
    }

    // ---- epilogue: C col = lane&15, row = (lane>>4)*4 + rr; direct stores ----
    // frag->coord: row = m0 + (mf&3)*32 + (mf>>2)*128 + wm*16 + rsub + rr
    //              col = n0 + nf*64 + wn*16 + lrow
    const int c0 = n0 + wn * 16;
    float bcol[4];
#pragma unroll
    for (int nf = 0; nf < 4; ++nf) bcol[nf] = bias[c0 + nf * 64 + lrow];
    const int rsub = (lane >> 4) * 4;

#pragma unroll
    for (int mf = 0; mf < 8; ++mf) {
        const int rbase = m0 + (mf & 3) * 32 + (mf >> 2) * 128 + wm * 16 + rsub;
#pragma unroll
        for (int rr = 0; rr < 4; ++rr) {
            int row = rbase + rr;
            int rt  = routing[row];
            size_t base = (size_t)row * N + c0 + lrow;
#pragma unroll
            for (int nf = 0; nf < 4; ++nf) {
                float v = gelu_f(acc[mf][nf][rr] + bcol[nf]);
                if (store_ob)    Ob[base + nf * 64] = f2bf(v);
                if (rt == match) Of[base + nf * 64] = v;
            }
        }
    }
}

extern "C" void kernel_launch(void* const* d_in, const int* in_sizes, int n_in,
                              void* d_out, int out_size, void* d_ws, size_t ws_size,
                              hipStream_t stream) {
    const float* x   = (const float*)d_in[0];
    const float* unc = (const float*)d_in[1];
    const float* Ws  = (const float*)d_in[2];
    const float* bs  = (const float*)d_in[3];
    const float* rw1 = (const float*)d_in[4];
    const float* rb1 = (const float*)d_in[5];
    const float* rw2 = (const float*)d_in[6];
    const float* rb2 = (const float*)d_in[7];
    const float* rw3 = (const float*)d_in[8];
    const float* rb3 = (const float*)d_in[9];
    float* out  = (float*)d_out;
    float* mask = out + (size_t)BATCH * DIM;

    // ws layout: Wb (8MB) | hb0 (32MB) | hb1 (32MB) | routing (32KB) | mm | flags
    char* ws = (char*)d_ws;
    unsigned short* Wb  = (unsigned short*)ws;
    unsigned short* hb0 = (unsigned short*)(ws + (size_t)8  * 1024 * 1024);
    unsigned short* hb1 = (unsigned short*)(ws + (size_t)40 * 1024 * 1024);
    int*   routing = (int*)  (ws + (size_t)72 * 1024 * 1024);
    float* mm      = (float*)(ws + (size_t)72 * 1024 * 1024 + 64 * 1024);
    int*   flags   = (int*)  (ws + (size_t)72 * 1024 * 1024 + 64 * 1024 + 16);

    minmax_k<<<1, 1024, 0, stream>>>(unc, mm, flags, BATCH);
    route_k<<<BATCH / 256, 256, 0, stream>>>(unc, mm, rw1, rb1, rw2, rb2, rw3, rb3,
                                             routing, mask, flags, BATCH);
    convx_k<<<(BATCH * DIM / 8 + 255) / 256, 256, 0, stream>>>(x, hb0, BATCH * DIM / 8);

    // chain: hb0(x) -W0-> hb1(lvl0) -W1-> hb0(lvl1) -W2-> hb1 -W3-> (lvl2, no Ob)
    const unsigned short* ins[4]  = {hb0, hb1, hb0, hb1};
    unsigned short*       outs[4] = {hb1, hb0, hb1, hb0};
    const int matches[4]   = {0, 1, -1, 2};
    const int store_ob[4]  = {1, 1, 1, 0};
    const int need_lvl[4]  = {0, 1, 2, 2};
    for (int l = 0; l < 4; ++l) {
        convw_k<<<dim3(32, 32), 256, 0, stream>>>(Ws + (size_t)l * DIM * DIM, Wb,
                                                  flags, need_lvl[l]);
        gemm_k<<<256, 512, 0, stream>>>(ins[l], Wb, outs[l], bs + (size_t)l * DIM,
                                        routing, out, matches[l], store_ob[l], need_lvl[l]);
    }
}

// Round 12
// 462.462 us; speedup vs baseline: 1.0912x; 1.0039x over previous
//
#include <hip/hip_runtime.h>
#include <hip/hip_bf16.h>

#define BATCH 8192
#define DIM   2048

typedef __attribute__((ext_vector_type(8))) short  bf16x8;
typedef __attribute__((ext_vector_type(4))) float  f32x4;

__device__ __forceinline__ unsigned short f2bf(float f) {
    __hip_bfloat16 h = __float2bfloat16(f);
    return *reinterpret_cast<unsigned short*>(&h);
}

// jax.nn.gelu approximate=True: 0.5x(1+tanh(y)) == x*sigmoid(2y), y=c0(x+0.044715x^3)
__device__ __forceinline__ float gelu_f(float x) {
    float z = -1.5957691216057308f * (x + 0.044715f * x * x * x);  // -2*c0*(...)
    return x / (1.0f + __expf(z));
}

__device__ __forceinline__ void gload_lds16(const void* g, void* lds) {
    __builtin_amdgcn_global_load_lds(
        (const __attribute__((address_space(1))) unsigned int*)g,
        (__attribute__((address_space(3))) unsigned int*)lds,
        16, 0, 0);
}

// ---------------- routing (self-contained: fused batch min/max) ----------------
// 32 blocks x 256. Each block redundantly reduces all 8192 uncertainties (~1us),
// stages router weights in LDS (fixes r2's 165us serial-s_load pathology), then
// computes its 256 samples' routing levels + f32 mask.
__global__ void route_k(const float* __restrict__ unc,
                        const float* __restrict__ rw1, const float* __restrict__ rb1,
                        const float* __restrict__ rw2, const float* __restrict__ rb2,
                        const float* __restrict__ rw3, const float* __restrict__ rb3,
                        int* __restrict__ routing, float* __restrict__ mask_out, int n) {
    __shared__ float s_w1[32], s_b1[32], s_w2[512], s_b2[16], s_w3[48], s_b3[3];
    __shared__ float red[8];
    const int t = threadIdx.x;

    // stage router weights
    if (t < 32) { s_w1[t] = rw1[t]; s_b1[t] = rb1[t]; }
#pragma unroll
    for (int i2 = 0; i2 < 2; ++i2) s_w2[i2 * 256 + t] = rw2[i2 * 256 + t];
    if (t < 16) s_b2[t] = rb2[t];
    if (t < 48) s_w3[t] = rw3[t];
    if (t < 3)  s_b3[t] = rb3[t];

    // block-redundant min/max over the whole batch
    float mn = 1e30f, mx = -1e30f;
    const float4* p = reinterpret_cast<const float4*>(unc);
    for (int i = t; i < n / 4; i += 256) {
        float4 a = p[i];
        mn = fminf(mn, fminf(fminf(a.x, a.y), fminf(a.z, a.w)));
        mx = fmaxf(mx, fmaxf(fmaxf(a.x, a.y), fmaxf(a.z, a.w)));
    }
#pragma unroll
    for (int o = 32; o > 0; o >>= 1) {
        mn = fminf(mn, __shfl_xor(mn, o));
        mx = fmaxf(mx, __shfl_xor(mx, o));
    }
    if ((t & 63) == 0) { red[t >> 6] = mn; red[4 + (t >> 6)] = mx; }
    __syncthreads();
    float gmn = fminf(fminf(red[0], red[1]), fminf(red[2], red[3]));
    float gmx = fmaxf(fmaxf(red[4], red[5]), fmaxf(red[6], red[7]));

    int i = blockIdx.x * 256 + t;
    if (i >= n) return;
    float u = (unc[i] - gmn) / (gmx - gmn + 1e-8f);
    float h1[32];
#pragma unroll
    for (int j = 0; j < 32; ++j) h1[j] = fmaxf(u * s_w1[j] + s_b1[j], 0.0f);
    float h2[16];
#pragma unroll
    for (int j = 0; j < 16; ++j) {
        float s = s_b2[j];
#pragma unroll
        for (int k = 0; k < 32; ++k) s += h1[k] * s_w2[k * 16 + j];
        h2[j] = fmaxf(s, 0.0f);
    }
    float lg[3];
#pragma unroll
    for (int j = 0; j < 3; ++j) {
        float s = s_b3[j];
#pragma unroll
        for (int k = 0; k < 16; ++k) s += h2[k] * s_w3[k * 3 + j];
        lg[j] = s;
    }
    // argmax(softmax) == argmax(logits); strict '>' = first-index ties (jnp.argmax)
    int idx = 0; float best = lg[0];
    if (lg[1] > best) { best = lg[1]; idx = 1; }
    if (lg[2] > best) { best = lg[2]; idx = 2; }
    routing[i] = idx;
    mask_out[i] = (float)idx;
}

// ---------------- conversion bodies ----------------
__device__ __forceinline__ void convx_body(const float* __restrict__ in,
                                           unsigned short* __restrict__ out, int i) {
    const float4* p = reinterpret_cast<const float4*>(in) + (size_t)2 * i;
    float4 a = p[0], b = p[1];
    bf16x8 o;
    o[0] = (short)f2bf(a.x); o[1] = (short)f2bf(a.y);
    o[2] = (short)f2bf(a.z); o[3] = (short)f2bf(a.w);
    o[4] = (short)f2bf(b.x); o[5] = (short)f2bf(b.y);
    o[6] = (short)f2bf(b.z); o[7] = (short)f2bf(b.w);
    *(reinterpret_cast<bf16x8*>(out) + i) = o;
}

// W [K][N] f32 -> Wt [N][K] bf16, 64x64 tile, full-line coalesced IO (r9).
__device__ __forceinline__ void convw_body(const float* __restrict__ W,
                                           unsigned short* __restrict__ Wt,
                                           float* lds, int n0, int k0, int t) {
#pragma unroll
    for (int i = 0; i < 4; ++i) {
        int r = (t >> 4) + 16 * i;       // k row 0..63
        int c4 = t & 15;                 // float4 col
        float4 v = *(const float4*)(W + (size_t)(k0 + r) * DIM + n0 + c4 * 4);
        lds[r * 65 + c4 * 4 + 0] = v.x;
        lds[r * 65 + c4 * 4 + 1] = v.y;
        lds[r * 65 + c4 * 4 + 2] = v.z;
        lds[r * 65 + c4 * 4 + 3] = v.w;
    }
    __syncthreads();
#pragma unroll
    for (int i = 0; i < 2; ++i) {
        int c2 = t + 256 * i;            // 0..511
        int nn = c2 >> 3;                // out row 0..63
        int kc = c2 & 7;                 // 8-elem k chunk
        bf16x8 o;
#pragma unroll
        for (int j = 0; j < 8; ++j) o[j] = (short)f2bf(lds[(kc * 8 + j) * 65 + nn]);
        *(bf16x8*)(Wt + (size_t)(n0 + nn) * DIM + k0 + kc * 8) = o;
    }
}

// Fused prep: blocks 0..8191 convert x -> bf16; blocks 8192..12287 convert all
// four W matrices -> transposed bf16 panels (concurrent instead of 5 serial
// launches). Used when ws_size fits 4 Wt panels.
__global__ void prep_k(const float* __restrict__ x, unsigned short* __restrict__ xb,
                       const float* __restrict__ Ws, unsigned short* __restrict__ Wt) {
    __shared__ float lds[64 * 65];
    const int b = blockIdx.x;
    if (b < BATCH) {                     // 8192 convx blocks
        convx_body(x, xb, b * 256 + threadIdx.x);
        return;
    }
    const int b2 = b - BATCH;            // 0..4095
    const int l  = b2 >> 10;             // layer 0..3
    const int cb = b2 & 1023;
    convw_body(Ws + (size_t)l * DIM * DIM, Wt + (size_t)l * DIM * DIM,
               lds, (cb & 31) * 64, (cb >> 5) * 64, threadIdx.x);
}

// standalone versions (fallback path when ws is small)
__global__ void convx_k(const float* __restrict__ in, unsigned short* __restrict__ out) {
    convx_body(in, out, blockIdx.x * 256 + threadIdx.x);
}
__global__ void convw_k(const float* __restrict__ W, unsigned short* __restrict__ Wt) {
    __shared__ float lds[64 * 65];
    convw_body(W, Wt, lds, blockIdx.x * 64, blockIdx.y * 64, threadIdx.x);
}

// ---------------- 256x256 8-phase GEMM, counted-vmcnt, 3-barrier/tile ----------------
// C[m][n] = gelu(sum_k A[m][k] * Bt[n][k] + bias[n])  -- r11 structure (74us/930TF):
// BM=BN=256, BK=64, 8 waves (2Mx4N), LDS 128KiB dbuf, counted vmcnt (6,6,-,4)
// never 0 mid-loop, only the 3 load-bearing barriers (each publishes a vmcnt),
// 16B-chunk XOR swizzle (chunk ^= row&7) on both sides -> 0 bank conflicts.
__launch_bounds__(512, 2)
__global__ void gemm_k(const unsigned short* __restrict__ A,
                       const unsigned short* __restrict__ Bt,
                       unsigned short* __restrict__ Ob,   // [M][N] bf16 scratch out
                       const float* __restrict__ bias,    // [N]
                       const int* __restrict__ routing,
                       float* __restrict__ Of,            // [M][N] f32 final out
                       int match, int store_ob, int need_lvl) {
    constexpr int N = DIM, K = DIM;
    constexpr int NT = K / 64;            // 32 K-tiles
    __shared__ char smem[131072];
    __shared__ int s_need;

    const int tid = threadIdx.x;
    // XCD-contiguous remap: 256 wgs, 8 XCDs -> XCD x owns wg [x*32, x*32+32)
    const int wg  = (blockIdx.x & 7) * 32 + (blockIdx.x >> 3);
    const int bm  = wg >> 3;              // 32 M-tiles
    const int bn  = wg & 7;               // 8 N-tiles
    const int m0  = bm * 256, n0 = bn * 256;

    if (need_lvl > 0) {
        if (tid == 0) s_need = 0;
        __syncthreads();
        if (tid < 256 && routing[m0 + tid] >= need_lvl) atomicOr(&s_need, 1);
        __syncthreads();
        if (s_need == 0) return;
    }

    const int wave = tid >> 6, lane = tid & 63;
    const int wm = wave >> 2, wn = wave & 3;      // 2M x 4N wave grid

    // ---- staging (linear LDS dest, inverse-swizzled global src) ----
    const int srow = tid >> 3;                              // 0..63
    const int sw8  = ((tid & 7) ^ (srow & 7)) << 3;         // inv-swizzled elem col
    const unsigned short* gA0 = A  + (size_t)(m0 + srow) * K + sw8;
    const unsigned short* gB0 = Bt + (size_t)(n0 + srow) * K + sw8;
    const int ldsw = wave * 1024;
    auto STAGE = [&](const unsigned short* gb, int koff, int lo) {
        gload_lds16(gb + koff,                  smem + lo + ldsw);
        gload_lds16(gb + (size_t)64 * K + koff, smem + lo + 8192 + ldsw);
    };
    const unsigned short* gA1 = gA0 + (size_t)128 * K;
    const unsigned short* gB1 = gB0 + (size_t)128 * K;

    f32x4 acc[8][4];
#pragma unroll
    for (int i = 0; i < 8; ++i)
#pragma unroll
        for (int j = 0; j < 4; ++j)
            acc[i][j] = (f32x4){0.f, 0.f, 0.f, 0.f};

    const int lrow = lane & 15;
    const int ck0 = (((lane >> 4)    ) ^ (lane & 7)) << 4;   // swizzled 16B chunk, ks=0
    const int ck1 = (((lane >> 4) + 4) ^ (lane & 7)) << 4;   // ks=1
    // per-lane LDS base offsets (constant across tiles); reads use imm offsets
    const int bA0 = (wm * 16 + lrow) * 128 + ck0;
    const int bA1 = (wm * 16 + lrow) * 128 + ck1;
    const int bB0 = 32768 + (wn * 16 + lrow) * 128 + ck0;
    const int bB1 = 32768 + (wn * 16 + lrow) * 128 + ck1;

    // prologue: stage tile 0 (order A0,B0,B1,A1), wait A0+B0, barrier
    STAGE(gA0, 0, 0);
    STAGE(gB0, 0, 32768);
    STAGE(gB1, 0, 49152);
    STAGE(gA1, 0, 16384);
    asm volatile("s_waitcnt vmcnt(4)" ::: "memory");
    __builtin_amdgcn_s_barrier();

    for (int t = 0; t < NT; ++t) {
        const char* buf = smem + ((t & 1) << 16);
        const int nb   = ((t & 1) << 16) ^ 65536;
        const int ko   = (t + 1) << 6;    // next tile's k elem offset
        const bool pre = (t + 1 < NT);
        const char* pA0 = buf + bA0;
        const char* pA1 = buf + bA1;
        const char* pB0 = buf + bB0;
        const char* pB1 = buf + bB1;
        bf16x8 aF[4][2], bL[2][2], bH[2][2];

        // ---- P0: read A-low + B-low; stage A0,B0(t+1); vmcnt(6); BARRIER
#pragma unroll
        for (int f = 0; f < 4; ++f) {
            aF[f][0] = *(const bf16x8*)(pA0 + f * 4096);
            aF[f][1] = *(const bf16x8*)(pA1 + f * 4096);
        }
#pragma unroll
        for (int g = 0; g < 2; ++g) {
            bL[g][0] = *(const bf16x8*)(pB0 + g * 8192);
            bL[g][1] = *(const bf16x8*)(pB1 + g * 8192);
        }
        if (pre) {
            STAGE(gA0, ko, nb);
            STAGE(gB0, ko, nb + 32768);
            asm volatile("s_waitcnt vmcnt(6)" ::: "memory");
        } else {
            asm volatile("s_waitcnt vmcnt(2)" ::: "memory");
        }
        __builtin_amdgcn_s_barrier();
        asm volatile("s_waitcnt lgkmcnt(0)" ::: "memory");
        __builtin_amdgcn_sched_barrier(0);
        __builtin_amdgcn_s_setprio(1);
#pragma unroll
        for (int ks = 0; ks < 2; ++ks)
#pragma unroll
            for (int f = 0; f < 4; ++f)
#pragma unroll
                for (int g = 0; g < 2; ++g)
                    acc[f][g] = __builtin_amdgcn_mfma_f32_16x16x32_bf16(
                        aF[f][ks], bL[g][ks], acc[f][g], 0, 0, 0);
        __builtin_amdgcn_s_setprio(0);

        // ---- P1: read B-high; stage B1(t+1); vmcnt(6); BARRIER
#pragma unroll
        for (int g = 0; g < 2; ++g) {
            bH[g][0] = *(const bf16x8*)(pB0 + 16384 + g * 8192);
            bH[g][1] = *(const bf16x8*)(pB1 + 16384 + g * 8192);
        }
        if (pre) {
            STAGE(gB1, ko, nb + 49152);
            asm volatile("s_waitcnt vmcnt(6)" ::: "memory");
        } else {
            asm volatile("s_waitcnt vmcnt(0)" ::: "memory");
        }
        __builtin_amdgcn_s_barrier();
        asm volatile("s_waitcnt lgkmcnt(0)" ::: "memory");
        __builtin_amdgcn_sched_barrier(0);
        __builtin_amdgcn_s_setprio(1);
#pragma unroll
        for (int ks = 0; ks < 2; ++ks)
#pragma unroll
            for (int f = 0; f < 4; ++f)
#pragma unroll
                for (int g = 0; g < 2; ++g)
                    acc[f][2 + g] = __builtin_amdgcn_mfma_f32_16x16x32_bf16(
                        aF[f][ks], bH[g][ks], acc[f][2 + g], 0, 0, 0);
        __builtin_amdgcn_s_setprio(0);

        // ---- P2: read A-high; stage A1(t+1); no barrier (A1(t) published at P1)
#pragma unroll
        for (int f = 0; f < 4; ++f) {
            aF[f][0] = *(const bf16x8*)(pA0 + 16384 + f * 4096);
            aF[f][1] = *(const bf16x8*)(pA1 + 16384 + f * 4096);
        }
        if (pre) STAGE(gA1, ko, nb + 16384);
        asm volatile("s_waitcnt lgkmcnt(0)" ::: "memory");
        __builtin_amdgcn_sched_barrier(0);
        __builtin_amdgcn_s_setprio(1);
#pragma unroll
        for (int ks = 0; ks < 2; ++ks)
#pragma unroll
            for (int f = 0; f < 4; ++f)
#pragma unroll
                for (int g = 0; g < 2; ++g)
                    acc[4 + f][2 + g] = __builtin_amdgcn_mfma_f32_16x16x32_bf16(
                        aF[f][ks], bH[g][ks], acc[4 + f][2 + g], 0, 0, 0);
        __builtin_amdgcn_s_setprio(0);

        // ---- P3: pure MFMA; tile-boundary counted wait vmcnt(4); BARRIER
        if (pre) asm volatile("s_waitcnt vmcnt(4)" ::: "memory");
        __builtin_amdgcn_s_barrier();
        __builtin_amdgcn_s_setprio(1);
#pragma unroll
        for (int ks = 0; ks < 2; ++ks)
#pragma unroll
            for (int f = 0; f < 4; ++f)
#pragma unroll
                for (int g = 0; g < 2; ++g)
                    acc[4 + f][g] = __builtin_amdgcn_mfma_f32_16x16x32_bf16(
                        aF[f][ks], bL[g][ks], acc[4 + f][g], 0, 0, 0);
        __builtin_amdgcn_s_setprio(0);
    }

    // ---- epilogue: C col = lane&15, row = (lane>>4)*4 + rr; direct stores ----
    const int c0 = n0 + wn * 16;
    float bcol[4];
#pragma unroll
    for (int nf = 0; nf < 4; ++nf) bcol[nf] = bias[c0 + nf * 64 + lrow];
    const int rsub = (lane >> 4) * 4;

#pragma unroll
    for (int mf = 0; mf < 8; ++mf) {
        const int rbase = m0 + (mf & 3) * 32 + (mf >> 2) * 128 + wm * 16 + rsub;
#pragma unroll
        for (int rr = 0; rr < 4; ++rr) {
            int row = rbase + rr;
            int rt  = routing[row];
            size_t base = (size_t)row * N + c0 + lrow;
#pragma unroll
            for (int nf = 0; nf < 4; ++nf) {
                float v = gelu_f(acc[mf][nf][rr] + bcol[nf]);
                if (store_ob)    Ob[base + nf * 64] = f2bf(v);
                if (rt == match) Of[base + nf * 64] = v;
            }
        }
    }
}

extern "C" void kernel_launch(void* const* d_in, const int* in_sizes, int n_in,
                              void* d_out, int out_size, void* d_ws, size_t ws_size,
                              hipStream_t stream) {
    const float* x   = (const float*)d_in[0];
    const float* unc = (const float*)d_in[1];
    const float* Ws  = (const float*)d_in[2];
    const float* bs  = (const float*)d_in[3];
    const float* rw1 = (const float*)d_in[4];
    const float* rb1 = (const float*)d_in[5];
    const float* rw2 = (const float*)d_in[6];
    const float* rb2 = (const float*)d_in[7];
    const float* rw3 = (const float*)d_in[8];
    const float* rb3 = (const float*)d_in[9];
    float* out  = (float*)d_out;
    float* mask = out + (size_t)BATCH * DIM;

    const size_t MB = 1024 * 1024;
    char* ws = (char*)d_ws;
    const bool big = ws_size >= 98 * MB;

    const int matches[4]   = {0, 1, -1, 2};
    const int store_ob[4]  = {1, 1, 1, 0};
    const int need_lvl[4]  = {0, 1, 2, 2};

    if (big) {
        // layout: Wt[4] (32MB) | hb0 (32MB) | hb1 (32MB) | routing (32KB)
        unsigned short* Wb  = (unsigned short*)ws;
        unsigned short* hb0 = (unsigned short*)(ws + 32 * MB);
        unsigned short* hb1 = (unsigned short*)(ws + 64 * MB);
        int* routing        = (int*)(ws + 96 * MB);

        route_k<<<32, 256, 0, stream>>>(unc, rw1, rb1, rw2, rb2, rw3, rb3,
                                        routing, mask, BATCH);
        prep_k<<<BATCH + 4096, 256, 0, stream>>>(x, hb0, Ws, Wb);

        const unsigned short* ins[4]  = {hb0, hb1, hb0, hb1};
        unsigned short*       outs[4] = {hb1, hb0, hb1, hb0};
        for (int l = 0; l < 4; ++l)
            gemm_k<<<256, 512, 0, stream>>>(ins[l], Wb + (size_t)l * DIM * DIM, outs[l],
                                            bs + (size_t)l * DIM, routing, out,
                                            matches[l], store_ob[l], need_lvl[l]);
    } else {
        // fallback layout: Wb (8MB) | hb0 (32MB) | hb1 (32MB) | routing (32KB)
        unsigned short* Wb  = (unsigned short*)ws;
        unsigned short* hb0 = (unsigned short*)(ws + 8 * MB);
        unsigned short* hb1 = (unsigned short*)(ws + 40 * MB);
        int* routing        = (int*)(ws + 72 * MB);

        route_k<<<32, 256, 0, stream>>>(unc, rw1, rb1, rw2, rb2, rw3, rb3,
                                        routing, mask, BATCH);
        convx_k<<<BATCH, 256, 0, stream>>>(x, hb0);

        const unsigned short* ins[4]  = {hb0, hb1, hb0, hb1};
        unsigned short*       outs[4] = {hb1, hb0, hb1, hb0};
        for (int l = 0; l < 4; ++l) {
            convw_k<<<dim3(32, 32), 256, 0, stream>>>(Ws + (size_t)l * DIM * DIM, Wb);
            gemm_k<<<256, 512, 0, stream>>>(ins[l], Wb, outs[l], bs + (size_t)l * DIM,
                                            routing, out, matches[l], store_ob[l], need_lvl[l]);
        }
    }
}